// Round 5
// baseline (496.991 us; speedup 1.0000x reference)
//
#include <hip/hip_runtime.h>

#define B_ 4096
#define T_ 512
#define F_ 8
#define H_ 16

typedef _Float16 half4_t __attribute__((ext_vector_type(4)));
typedef _Float16 half2_t __attribute__((ext_vector_type(2)));
typedef __fp16 fp16x2_t __attribute__((ext_vector_type(2)));
typedef float f32x4 __attribute__((ext_vector_type(4)));

__device__ __forceinline__ f32x4 mfma16(half4_t a, half4_t b, f32x4 c) {
    return __builtin_amdgcn_mfma_f32_16x16x16f16(a, b, c, 0, 0, 0);
}
__device__ __forceinline__ float rcpf_(float x) { return __builtin_amdgcn_rcpf(x); }
__device__ __forceinline__ float exp2f_(float x) { return __builtin_amdgcn_exp2f(x); }

#define L2E 1.44269504088896340736f

// fast pack 4 f32 -> 4 f16 (2x v_cvt_pkrtz)
__device__ __forceinline__ half4_t pack4(float a, float b, float c, float d) {
    half2_t lo = __builtin_bit_cast(half2_t, __builtin_amdgcn_cvt_pkrtz(a, b));
    half2_t hi = __builtin_bit_cast(half2_t, __builtin_amdgcn_cvt_pkrtz(c, d));
    half4_t r;
    r[0] = lo[0]; r[1] = lo[1]; r[2] = hi[0]; r[3] = hi[1];
    return r;
}

// gates are PRESCALED: i,f,o rows by log2(e); g rows by 2*log2(e).
// sigmoid(x) = rcp(1+exp2(-x')); tanh(g) = 1-2*rcp(1+exp2(g')).
__device__ __forceinline__ half4_t lstm_act(const f32x4 di, const f32x4 df,
                                            const f32x4 dg, const f32x4 dq,
                                            f32x4& c) {
    float h[4];
#pragma unroll
    for (int u = 0; u < 4; ++u) {
        const float ii = rcpf_(1.0f + exp2f_(-di[u]));
        const float ff = rcpf_(1.0f + exp2f_(-df[u]));
        const float gg = 1.0f - 2.0f * rcpf_(1.0f + exp2f_(dg[u]));
        const float oo = rcpf_(1.0f + exp2f_(-dq[u]));
        const float cn = ff * c[u] + ii * gg;
        c[u] = cn;
        const float th = 1.0f - 2.0f * rcpf_(1.0f + exp2f_((2.0f * L2E) * cn));
        h[u] = oo * th;
    }
    return pack4(h[0], h[1], h[2], h[3]);
}

// One wave = 16 chains. MFMA 16x16x16_f16 layout (verified round 3):
//   A[m=lane&15][k=4q+i], B[k=4q+i][n=lane&15], D[r=4q+i][n=lane&15], q=lane>>4.
// cols n = chains, rows = gate rows. Lane (q,n) gets all 4 gates for units
// 4q..4q+3 of chain n; h packs straight into the next step's B-fragment.
// Recurrence critical path: 1 MFMA -> activations -> pack (xproj MFMAs are
// issued off-path, one step ahead; their D feeds the next hh MFMA's C).
__global__ __launch_bounds__(64, 1) void lstm_ae_mfma(
    const float* __restrict__ x,
    const float* __restrict__ eWih, const float* __restrict__ eWhh,
    const float* __restrict__ ebih, const float* __restrict__ ebhh,
    const float* __restrict__ dWih, const float* __restrict__ dWhh,
    const float* __restrict__ dbih, const float* __restrict__ dbhh,
    const float* __restrict__ oW,   const float* __restrict__ ob,
    float* __restrict__ out)
{
    const int lane = threadIdx.x & 63;
    const int q = lane >> 4;
    const int n = lane & 15;
    const int chain = blockIdx.x * 16 + n;
    const float sg0 = L2E, sg2 = 2.0f * L2E;

    // ---------------- encoder weight fragments (prescaled) ----------------
    half4_t eAhh[4], eAih[4];
    f32x4 eBias[4];
#pragma unroll
    for (int g = 0; g < 4; ++g) {
        const float s = (g == 2) ? sg2 : sg0;
        const int row = g * 16 + n;
        {
            const float4 w = *(const float4*)(eWhh + row * 16 + 4 * q);
            eAhh[g] = half4_t{(_Float16)(s * w.x), (_Float16)(s * w.y),
                              (_Float16)(s * w.z), (_Float16)(s * w.w)};
        }
        if (q < 2) {
            const float4 w = *(const float4*)(eWih + row * 8 + 4 * q);
            eAih[g] = half4_t{(_Float16)(s * w.x), (_Float16)(s * w.y),
                              (_Float16)(s * w.z), (_Float16)(s * w.w)};
        } else {
            eAih[g] = half4_t{(_Float16)0.f, (_Float16)0.f, (_Float16)0.f, (_Float16)0.f};
        }
        const int rb = g * 16 + 4 * q;
        eBias[g] = f32x4{s * (ebih[rb]     + ebhh[rb]),
                         s * (ebih[rb + 1] + ebhh[rb + 1]),
                         s * (ebih[rb + 2] + ebhh[rb + 2]),
                         s * (ebih[rb + 3] + ebhh[rb + 3])};
    }

    // all lanes load x (q>=2 mirror q&1; their A-cols are zero so values
    // never reach D) -> branch-free streaming
    const float* xptr = x + (size_t)chain * (T_ * F_) + 4 * (q & 1);

    half4_t hB = half4_t{(_Float16)0.f, (_Float16)0.f, (_Float16)0.f, (_Float16)0.f};
    f32x4 cS = f32x4{0.f, 0.f, 0.f, 0.f};

    float4 x0  = *(const float4*)(xptr);
    float4 xq0 = *(const float4*)(xptr + 1 * F_);
    float4 xq1 = *(const float4*)(xptr + 2 * F_);
    float4 xq2 = *(const float4*)(xptr + 3 * F_);
    float4 xq3 = *(const float4*)(xptr + 4 * F_);
    float4 xq4 = *(const float4*)(xptr + 5 * F_);
    float4 xq5 = *(const float4*)(xptr + 6 * F_);

    f32x4 xpC[4];
    {
        const half4_t xB = pack4(x0.x, x0.y, x0.z, x0.w);
#pragma unroll
        for (int g = 0; g < 4; ++g) xpC[g] = mfma16(eAih[g], xB, eBias[g]);
    }

    // ---------------- encoder ----------------
    for (int t = 0; t < T_; t += 2) {
        // step t: hh MFMAs on path; xproj(t+1) behind them
        f32x4 di = mfma16(eAhh[0], hB, xpC[0]);
        f32x4 df = mfma16(eAhh[1], hB, xpC[1]);
        f32x4 dg = mfma16(eAhh[2], hB, xpC[2]);
        f32x4 dq = mfma16(eAhh[3], hB, xpC[3]);
        {
            const half4_t xB = pack4(xq0.x, xq0.y, xq0.z, xq0.w);
            xpC[0] = mfma16(eAih[0], xB, eBias[0]);
            xpC[1] = mfma16(eAih[1], xB, eBias[1]);
            xpC[2] = mfma16(eAih[2], xB, eBias[2]);
            xpC[3] = mfma16(eAih[3], xB, eBias[3]);
        }
        hB = lstm_act(di, df, dg, dq, cS);

        // step t+1
        di = mfma16(eAhh[0], hB, xpC[0]);
        df = mfma16(eAhh[1], hB, xpC[1]);
        dg = mfma16(eAhh[2], hB, xpC[2]);
        dq = mfma16(eAhh[3], hB, xpC[3]);
        {
            const half4_t xB = pack4(xq1.x, xq1.y, xq1.z, xq1.w);
            xpC[0] = mfma16(eAih[0], xB, eBias[0]);
            xpC[1] = mfma16(eAih[1], xB, eBias[1]);
            xpC[2] = mfma16(eAih[2], xB, eBias[2]);
            xpC[3] = mfma16(eAih[3], xB, eBias[3]);
        }
        hB = lstm_act(di, df, dg, dq, cS);

        // rotate + prefetch (distance ~7 steps)
        xq0 = xq2; xq1 = xq3; xq2 = xq4; xq3 = xq5;
        const int t7 = (t + 7 < T_) ? t + 7 : T_ - 1;
        const int t8 = (t + 8 < T_) ? t + 8 : T_ - 1;
        xq4 = *(const float4*)(xptr + t7 * F_);
        xq5 = *(const float4*)(xptr + t8 * F_);
    }

    // ------------- decoder weights + constant input projection -------------
    half4_t dAhh[4], oA;
    f32x4 dCc[4];
#pragma unroll
    for (int g = 0; g < 4; ++g) {
        const float s = (g == 2) ? sg2 : sg0;
        const int row = g * 16 + n;
        {
            const float4 w = *(const float4*)(dWih + row * 16 + 4 * q);
            const half4_t a = half4_t{(_Float16)(s * w.x), (_Float16)(s * w.y),
                                      (_Float16)(s * w.z), (_Float16)(s * w.w)};
            const int rb = g * 16 + 4 * q;
            const f32x4 bs = f32x4{s * (dbih[rb]     + dbhh[rb]),
                                   s * (dbih[rb + 1] + dbhh[rb + 1]),
                                   s * (dbih[rb + 2] + dbhh[rb + 2]),
                                   s * (dbih[rb + 3] + dbhh[rb + 3])};
            dCc[g] = mfma16(a, hB, bs);   // hB == h_T here
        }
        {
            const float4 w = *(const float4*)(dWhh + row * 16 + 4 * q);
            dAhh[g] = half4_t{(_Float16)(s * w.x), (_Float16)(s * w.y),
                              (_Float16)(s * w.z), (_Float16)(s * w.w)};
        }
    }
    if (n < 8) {
        const float4 w = *(const float4*)(oW + n * 16 + 4 * q);
        oA = half4_t{(_Float16)w.x, (_Float16)w.y, (_Float16)w.z, (_Float16)w.w};
    } else {
        oA = half4_t{(_Float16)0.f, (_Float16)0.f, (_Float16)0.f, (_Float16)0.f};
    }
    const int obase = (4 * q) & 7;  // q>=2 lanes read valid-but-unused bias
    const f32x4 oC = f32x4{ob[obase], ob[obase + 1], ob[obase + 2], ob[obase + 3]};

    hB = half4_t{(_Float16)0.f, (_Float16)0.f, (_Float16)0.f, (_Float16)0.f};
    cS = f32x4{0.f, 0.f, 0.f, 0.f};

    float* outp = out + (size_t)chain * (T_ * F_) + 4 * q;  // valid for q<2

    // ---------------- decoder + fused output projection ----------------
#pragma unroll 2
    for (int t = 0; t < T_; ++t) {
        f32x4 di = mfma16(dAhh[0], hB, dCc[0]);
        f32x4 df = mfma16(dAhh[1], hB, dCc[1]);
        f32x4 dg = mfma16(dAhh[2], hB, dCc[2]);
        f32x4 dq = mfma16(dAhh[3], hB, dCc[3]);
        hB = lstm_act(di, df, dg, dq, cS);
        const f32x4 ov = mfma16(oA, hB, oC);   // off the recurrence path
        if (q < 2) {
            *(float4*)(outp + t * F_) = make_float4(ov[0], ov[1], ov[2], ov[3]);
        }
    }
}

extern "C" void kernel_launch(void* const* d_in, const int* in_sizes, int n_in,
                              void* d_out, int out_size, void* d_ws, size_t ws_size,
                              hipStream_t stream) {
    (void)in_sizes; (void)n_in; (void)d_ws; (void)ws_size; (void)out_size;
    lstm_ae_mfma<<<dim3(B_ / 16), dim3(64), 0, stream>>>(
        (const float*)d_in[0],
        (const float*)d_in[1], (const float*)d_in[2],
        (const float*)d_in[3], (const float*)d_in[4],
        (const float*)d_in[5], (const float*)d_in[6],
        (const float*)d_in[7], (const float*)d_in[8],
        (const float*)d_in[9], (const float*)d_in[10],
        (float*)d_out);
}

// Round 6
// 483.727 us; speedup vs baseline: 1.0274x; 1.0274x over previous
//
#include <hip/hip_runtime.h>

#define B_ 4096
#define T_ 512
#define F_ 8
#define H_ 16

typedef float f32x2 __attribute__((ext_vector_type(2)));
typedef float f32x4 __attribute__((ext_vector_type(4)));

__device__ __forceinline__ f32x2 pkfma(f32x2 a, f32x2 b, f32x2 c) {
    return __builtin_elementwise_fma(a, b, c);
}
__device__ __forceinline__ float rcpf_(float x) { return __builtin_amdgcn_rcpf(x); }
__device__ __forceinline__ float exp2f_(float x) { return __builtin_amdgcn_exp2f(x); }

#define L2E 1.44269504088896340736f

// One WAVE per batch chain (4096 waves -> 4 waves/SIMD across 1024 SIMDs).
// lane: unit j = lane>>2, gate g = lane&3 (0=i,1=f,2=g,3=o); weight row
// r = g*16+j. Gate pre-activations are PRESCALED by sG = -log2e (sigmoid
// rows) or +2log2e (tanh row) so the activation is one uniform
// exp2/rcp/fma for all lanes. Quad-internal shfl_xor(1,2,3) gathers the 4
// gates of unit j; all 4 lanes redundantly compute identical c_j, h_j.
// h broadcast: conflict-free LDS write (4 padded 80B regions) + 4
// broadcast ds_read_b128. Recurrence path ~250 cyc, hidden by 4-way
// wave interleave; kernel is VALU-issue-bound by design.
__global__ __launch_bounds__(64, 4) void lstm_ae_w64(
    const float* __restrict__ x,
    const float* __restrict__ eWih, const float* __restrict__ eWhh,
    const float* __restrict__ ebih, const float* __restrict__ ebhh,
    const float* __restrict__ dWih, const float* __restrict__ dWhh,
    const float* __restrict__ dbih, const float* __restrict__ dbhh,
    const float* __restrict__ oW,   const float* __restrict__ ob,
    float* __restrict__ out)
{
    const int lane = threadIdx.x;     // 0..63
    const int g = lane & 3;           // gate 0=i,1=f,2=g,3=o
    const int j = lane >> 2;          // hidden unit 0..15
    const int r = g * 16 + j;         // weight row in PyTorch gate order
    const int chain = blockIdx.x;

    __shared__ __align__(16) float hsh[80];    // 4 regions x 20 floats
    __shared__ __align__(16) float xsh[256];   // 32 steps x 8 features

    const float sG = (g == 2) ? (2.0f * L2E) : (-L2E);
    const float mA = (g == 2) ? -2.0f : 1.0f;
    const float mB = (g == 2) ? 1.0f : 0.0f;
    const bool gb0 = (g & 1) != 0, gb1 = (g & 2) != 0;

    // ---------------- encoder weights (prescaled, registers) --------------
    f32x2 wr[8], wi[4];
#pragma unroll
    for (int k = 0; k < 8; ++k)
        wr[k] = f32x2{sG * eWhh[r * 16 + 2 * k], sG * eWhh[r * 16 + 2 * k + 1]};
#pragma unroll
    for (int k = 0; k < 4; ++k)
        wi[k] = f32x2{sG * eWih[r * 8 + 2 * k], sG * eWih[r * 8 + 2 * k + 1]};
    const float ebias = sG * (ebih[r] + ebhh[r]);

    const int wofs = g * 20 + j;   // LDS h write slot (region g, unit j)
    const int rofs = g * 20;       // LDS h read region (any region works)

    const float* xb = x + (size_t)chain * (T_ * F_);

    // stage x chunk 0, prefetch chunk 1 (1 KB coalesced per chunk)
    float4 pf = *(const float4*)(xb + lane * 4);
    *(float4*)&xsh[lane * 4] = pf;
    pf = *(const float4*)(xb + 256 + lane * 4);

    f32x2 hv[8];
#pragma unroll
    for (int p = 0; p < 8; ++p) hv[p] = f32x2{0.f, 0.f};
    float c = 0.f;

    // xp for step 0
    float xp;
    {
        const f32x4 xv0 = *(const f32x4*)&xsh[0];
        const f32x4 xv1 = *(const f32x4*)&xsh[4];
        f32x2 a = f32x2{ebias, 0.f};
        a = pkfma(wi[0], f32x2{xv0[0], xv0[1]}, a);
        a = pkfma(wi[1], f32x2{xv0[2], xv0[3]}, a);
        a = pkfma(wi[2], f32x2{xv1[0], xv1[1]}, a);
        a = pkfma(wi[3], f32x2{xv1[2], xv1[3]}, a);
        xp = a[0] + a[1];
    }

    // ---------------- encoder ----------------
    for (int t = 0; t < T_; ++t) {
        // gate pre-activation (prescaled): xp + Whh.h
        f32x2 acc = f32x2{xp, 0.f};
#pragma unroll
        for (int p = 0; p < 8; ++p) acc = pkfma(wr[p], hv[p], acc);
        const float gate = acc[0] + acc[1];

        // unified activation
        const float ev = exp2f_(gate);
        const float rv = rcpf_(1.0f + ev);
        const float act = __builtin_fmaf(rv, mA, mB);

        // gather quad's 4 gate activations (a_k holds gate g^k)
        const float a1 = __shfl_xor(act, 1);
        const float a2 = __shfl_xor(act, 2);
        const float a3 = __shfl_xor(act, 3);

        const float p02 = act * a2, p13 = a1 * a3;
        const float ig = gb0 ? p13 : p02;                      // i*g
        const float fv = gb0 ? (gb1 ? a2 : act) : (gb1 ? a3 : a1);  // f
        const float ov = gb0 ? (gb1 ? act : a2) : (gb1 ? a1 : a3);  // o

        c = __builtin_fmaf(fv, c, ig);
        const float e2 = exp2f_((2.0f * L2E) * c);
        const float tr = rcpf_(1.0f + e2);
        const float th = __builtin_fmaf(tr, -2.0f, 1.0f);      // tanh(c)
        const float h = ov * th;

        // h broadcast: write own slot, read full h (broadcast reads)
        hsh[wofs] = h;
        const f32x4 h0 = *(const f32x4*)&hsh[rofs];
        const f32x4 h1 = *(const f32x4*)&hsh[rofs + 4];
        const f32x4 h2 = *(const f32x4*)&hsh[rofs + 8];
        const f32x4 h3 = *(const f32x4*)&hsh[rofs + 12];
        hv[0] = f32x2{h0[0], h0[1]}; hv[1] = f32x2{h0[2], h0[3]};
        hv[2] = f32x2{h1[0], h1[1]}; hv[3] = f32x2{h1[2], h1[3]};
        hv[4] = f32x2{h2[0], h2[1]}; hv[5] = f32x2{h2[2], h2[3]};
        hv[6] = f32x2{h3[0], h3[1]}; hv[7] = f32x2{h3[2], h3[3]};

        // stage next chunk at chunk boundary (prefetched 32 steps ago)
        if ((t & 31) == 31 && t + 1 < T_) {
            *(float4*)&xsh[lane * 4] = pf;
            const int nc = (t >> 5) + 2;
            if (nc < 16) pf = *(const float4*)(xb + nc * 256 + lane * 4);
        }
        // xp for step t+1 (off the critical path)
        const int nidx = ((t + 1) & 31) * 8;
        const f32x4 xv0 = *(const f32x4*)&xsh[nidx];
        const f32x4 xv1 = *(const f32x4*)&xsh[nidx + 4];
        f32x2 xa = f32x2{ebias, 0.f};
        xa = pkfma(wi[0], f32x2{xv0[0], xv0[1]}, xa);
        xa = pkfma(wi[1], f32x2{xv0[2], xv0[3]}, xa);
        xa = pkfma(wi[2], f32x2{xv1[0], xv1[1]}, xa);
        xa = pkfma(wi[3], f32x2{xv1[2], xv1[3]}, xa);
        xp = xa[0] + xa[1];
    }

    // ------------- decoder weights + constant input projection ------------
#pragma unroll
    for (int k = 0; k < 8; ++k)
        wr[k] = f32x2{sG * dWhh[r * 16 + 2 * k], sG * dWhh[r * 16 + 2 * k + 1]};
    float udec;
    {
        f32x2 a = f32x2{sG * (dbih[r] + dbhh[r]), 0.f};
#pragma unroll
        for (int k = 0; k < 8; ++k)
            a = pkfma(f32x2{sG * dWih[r * 16 + 2 * k], sG * dWih[r * 16 + 2 * k + 1]},
                      hv[k], a);   // hv == h_T
        udec = a[0] + a[1];
    }
    const int ro = lane & 7;
    f32x2 wo[8];
#pragma unroll
    for (int k = 0; k < 8; ++k)
        wo[k] = f32x2{oW[ro * 16 + 2 * k], oW[ro * 16 + 2 * k + 1]};
    const float obv = ob[ro];

#pragma unroll
    for (int p = 0; p < 8; ++p) hv[p] = f32x2{0.f, 0.f};
    c = 0.f;
    float* outp = out + (size_t)chain * (T_ * F_);

    // ---------------- decoder + fused output projection ----------------
    for (int t = 0; t < T_; ++t) {
        f32x2 acc = f32x2{udec, 0.f};
#pragma unroll
        for (int p = 0; p < 8; ++p) acc = pkfma(wr[p], hv[p], acc);
        const float gate = acc[0] + acc[1];

        const float ev = exp2f_(gate);
        const float rv = rcpf_(1.0f + ev);
        const float act = __builtin_fmaf(rv, mA, mB);

        const float a1 = __shfl_xor(act, 1);
        const float a2 = __shfl_xor(act, 2);
        const float a3 = __shfl_xor(act, 3);

        const float p02 = act * a2, p13 = a1 * a3;
        const float ig = gb0 ? p13 : p02;
        const float fv = gb0 ? (gb1 ? a2 : act) : (gb1 ? a3 : a1);
        const float ov = gb0 ? (gb1 ? act : a2) : (gb1 ? a1 : a3);

        c = __builtin_fmaf(fv, c, ig);
        const float e2 = exp2f_((2.0f * L2E) * c);
        const float tr = rcpf_(1.0f + e2);
        const float th = __builtin_fmaf(tr, -2.0f, 1.0f);
        const float h = ov * th;

        hsh[wofs] = h;
        const f32x4 h0 = *(const f32x4*)&hsh[rofs];
        const f32x4 h1 = *(const f32x4*)&hsh[rofs + 4];
        const f32x4 h2 = *(const f32x4*)&hsh[rofs + 8];
        const f32x4 h3 = *(const f32x4*)&hsh[rofs + 12];
        hv[0] = f32x2{h0[0], h0[1]}; hv[1] = f32x2{h0[2], h0[3]};
        hv[2] = f32x2{h1[0], h1[1]}; hv[3] = f32x2{h1[2], h1[3]};
        hv[4] = f32x2{h2[0], h2[1]}; hv[5] = f32x2{h2[2], h2[3]};
        hv[6] = f32x2{h3[0], h3[1]}; hv[7] = f32x2{h3[2], h3[3]};

        // output projection: every lane has full h; lanes 0..7 store
        f32x2 oa = f32x2{obv, 0.f};
#pragma unroll
        for (int p = 0; p < 8; ++p) oa = pkfma(wo[p], hv[p], oa);
        if (lane < 8) outp[t * F_ + ro] = oa[0] + oa[1];
    }
}

extern "C" void kernel_launch(void* const* d_in, const int* in_sizes, int n_in,
                              void* d_out, int out_size, void* d_ws, size_t ws_size,
                              hipStream_t stream) {
    (void)in_sizes; (void)n_in; (void)d_ws; (void)ws_size; (void)out_size;
    lstm_ae_w64<<<dim3(B_), dim3(64), 0, stream>>>(
        (const float*)d_in[0],
        (const float*)d_in[1], (const float*)d_in[2],
        (const float*)d_in[3], (const float*)d_in[4],
        (const float*)d_in[5], (const float*)d_in[6],
        (const float*)d_in[7], (const float*)d_in[8],
        (const float*)d_in[9], (const float*)d_in[10],
        (float*)d_out);
}